// Round 4
// baseline (534.279 us; speedup 1.0000x reference)
//
#include <hip/hip_runtime.h>
#include <math.h>

#define NIMG 116          // 4*29 images
#define TW 118            // output tile width  (phase-1 columns = TW+10 = 128)
#define TH 16             // output tile height (strips of 8 rows, 2 strips)

// 11-tap Gaussian (size=11, sigma=1.5), fp32 values matching the reference.
static constexpr float W[11] = {
    0.00102838f, 0.00759876f, 0.03600078f, 0.10936075f, 0.21300554f,
    0.26601172f, 0.21300554f, 0.10936075f, 0.03600078f, 0.00759876f,
    0.00102838f};

__device__ __forceinline__ float frcp(float x) {
    return __builtin_amdgcn_rcpf(x);
}

__device__ __forceinline__ float fsig(float x) {
    float e = __builtin_amdgcn_exp2f(x * -1.4426950408889634f);
    return frcp(1.0f + e);
}

// One block per TWxTH output tile. Phase 1: vertical Gaussian of
// {X,Y,XX,(YY),XY} (thread-per-column, register accumulators, pool fused).
// Phase 2: horizontal Gaussian from LDS via swizzled float4 reads + SSIM map.
// SKIPYY: targets are binary (Y*Y==Y exactly) -> filter(YY)==filter(Y),
//         sigma2_sq = mu2 - mu2^2. Drops 1 of 5 quantities everywhere.
// NARROW: N <= 128 -> one x-tile covers all columns (phase-1 width 128).
template <bool SIG, bool POOL, bool SKIPYY, bool NARROW, int MINW>
__global__ __launch_bounds__(256, MINW)
void ssim_kernel(const float* __restrict__ X, const float* __restrict__ Y,
                 int N, int M,
                 float* __restrict__ accSsim, float* __restrict__ accCs,
                 float* __restrict__ poolX, float* __restrict__ poolY) {
    constexpr int Q = SKIPYY ? 4 : 5;          // mu1, mu2, xx, (yy), xy
    __shared__ float smem[Q * 16 * 128];       // 32KB (Q=4) / 40KB (Q=5)

    const int tid = threadIdx.x;
    const int img = blockIdx.z;
    const int ox0 = NARROW ? 0 : blockIdx.x * TW;
    const int oy0 = blockIdx.y * TH;
    const long base = (long)img * N * N;

    // ================= phase 1: vertical filter (+fused 2x2 pool) ==========
    const int c  = tid & 127;      // tile-local column 0..127
    const int s  = tid >> 7;       // strip 0/1 (rows 8s .. 8s+7 of v)
    const int ci = ox0 + c;        // global column
    const int cic = min(ci, N - 1);
    const int half = N >> 1;
    const int powned = NARROW ? N : min(TW, N - ox0);  // pool column ownership

    const float* __restrict__ Xb = X + base;
    const float* __restrict__ Yb = Y + base;

    float a0[8], a1[8], a2[8], a4[8];
    float a3[SKIPYY ? 1 : 8];
#pragma unroll
    for (int o = 0; o < 8; o++) {
        a0[o] = a1[o] = a2[o] = a4[o] = 0.f;
        if constexpr (!SKIPYY) a3[o] = 0.f;
    }

    float px = 0.f, py = 0.f;
#pragma unroll
    for (int i = 0; i < 18; i++) {
        int row = oy0 + 8 * s + i;
        int rc = min(row, N - 1);
        float x = Xb[(long)rc * N + cic];
        float y = Yb[(long)rc * N + cic];
        if (SIG) x = fsig(x);
        float xx = x * x, xy = x * y;
#pragma unroll
        for (int o = 0; o < 8; o++) {
            int t = i - o;
            if (t >= 0 && t < 11) {          // folds statically after unroll
                a0[o] = fmaf(W[t], x,  a0[o]);
                a1[o] = fmaf(W[t], y,  a1[o]);
                a2[o] = fmaf(W[t], xx, a2[o]);
                if constexpr (!SKIPYY) a3[o] = fmaf(W[t], y * y, a3[o]);
                a4[o] = fmaf(W[t], xy, a4[o]);
            }
        }
        if (POOL && (i & 1) && i < 8) {
            float cx = px + x, cy = py + y;
            float rx = __shfl_down(cx, 1, 64);   // column c+1 (same wave)
            float ry = __shfl_down(cy, 1, 64);
            if (!(c & 1) && c < powned) {
                int orow = (oy0 + 8 * s + i - 1) >> 1;
                int ocol = ci >> 1;
                long pb = (long)img * half * half + (long)orow * half + ocol;
                poolX[pb] = 0.25f * (cx + rx);
                poolY[pb] = 0.25f * (cy + ry);
            }
        }
        px = x; py = y;
    }

    // store v to LDS, column-swizzled by 4*row to spread b128 read banks
#pragma unroll
    for (int o = 0; o < 8; o++) {
        int r = 8 * s + o;
        int cc = (c + 4 * r) & 127;
        smem[0 * 2048 + r * 128 + cc] = a0[o];
        smem[1 * 2048 + r * 128 + cc] = a1[o];
        smem[2 * 2048 + r * 128 + cc] = a2[o];
        if constexpr (!SKIPYY) smem[3 * 2048 + r * 128 + cc] = a3[o];
        smem[(Q - 1) * 2048 + r * 128 + cc] = a4[o];
    }
    __syncthreads();

    // ================= phase 2: horizontal filter + SSIM ====================
    const float C1 = 1e-4f, C2 = 9e-4f;
    float scs = 0.f, sss = 0.f;
    {
        const int r = tid >> 4;    // output row within tile
        const int k = tid & 15;    // 8-px column segment
        if (k < 15) {              // segment base 8k must be < 118
            float acc[Q][8];
#pragma unroll
            for (int q = 0; q < Q; q++) {
                float rg[20];
#pragma unroll
                for (int j5 = 0; j5 < 5; j5++) {
                    int col = (8 * k + 4 * j5 + 4 * r) & 127;   // swizzled chunk
                    const float4 v4 = *(const float4*)&smem[q * 2048 + r * 128 + col];
                    rg[4 * j5 + 0] = v4.x; rg[4 * j5 + 1] = v4.y;
                    rg[4 * j5 + 2] = v4.z; rg[4 * j5 + 3] = v4.w;
                }
#pragma unroll
                for (int j = 0; j < 8; j++) {
                    float a = 0.f;
#pragma unroll
                    for (int t = 0; t < 11; t++) a = fmaf(W[t], rg[j + t], a);
                    acc[q][j] = a;
                }
            }
            int gy = oy0 + r;
#pragma unroll
            for (int j = 0; j < 8; j++) {
                int lc = 8 * k + j;
                int gx = ox0 + lc;
                if (lc < TW && gx < M && gy < M) {
                    float mu1 = acc[0][j], mu2 = acc[1][j];
                    float exx = acc[2][j], exy = acc[Q - 1][j];
                    float m11 = mu1 * mu1, m22 = mu2 * mu2, m12 = mu1 * mu2;
                    float s1 = exx - m11;
                    float s2 = SKIPYY ? (mu2 - m22) : (acc[3][j] - m22);
                    float s12 = exy - m12;
                    float cs = (2.f * s12 + C2) * frcp(s1 + s2 + C2);
                    float ssim = (2.f * m12 + C1) * frcp(m11 + m22 + C1) * cs;
                    scs += cs; sss += ssim;
                }
            }
        }
    }

    // block reduction (reuse smem after barrier)
    for (int off = 32; off > 0; off >>= 1) {
        scs += __shfl_down(scs, off, 64);
        sss += __shfl_down(sss, off, 64);
    }
    __syncthreads();
    int lane = tid & 63, wv = tid >> 6;
    if (lane == 0) { smem[wv] = scs; smem[4 + wv] = sss; }
    __syncthreads();
    if (tid == 0) {
        atomicAdd(&accCs[img],   smem[0] + smem[1] + smem[2] + smem[3]);
        atomicAdd(&accSsim[img], smem[4] + smem[5] + smem[6] + smem[7]);
    }
}

// acc layout: level l -> [l*2*NIMG .. +NIMG) ssim sums, [+NIMG .. +2*NIMG) cs sums
__global__ __launch_bounds__(128)
void finalize_kernel(const float* __restrict__ acc, float* __restrict__ out) {
    const float wts[5] = {0.0448f, 0.2856f, 0.3001f, 0.2363f, 0.1333f};
    const int Ms[5] = {502, 246, 118, 54, 22};
    int t = threadIdx.x;
    float v = 0.f;
    if (t < NIMG) {
        float prod = 1.f;
#pragma unroll
        for (int l = 0; l < 5; l++) {
            float inv = 1.0f / ((float)Ms[l] * (float)Ms[l]);
            float m = (l < 4) ? acc[l * 2 * NIMG + NIMG + t] * inv   // cs mean
                              : acc[l * 2 * NIMG + t] * inv;          // ssim mean
            m = fmaxf(m, 0.f);                                        // relu
            prod *= powf(m, wts[l]);
        }
        v = prod;
    }
    for (int off = 32; off > 0; off >>= 1) v += __shfl_down(v, off, 64);
    __shared__ float red[2];
    if ((t & 63) == 0) red[t >> 6] = v;
    __syncthreads();
    if (t == 0) out[0] = 1.0f - (red[0] + red[1]) / (float)NIMG;
}

extern "C" void kernel_launch(void* const* d_in, const int* in_sizes, int n_in,
                              void* d_out, int out_size, void* d_ws, size_t ws_size,
                              hipStream_t stream) {
    const float* logits = (const float*)d_in[0];
    const float* targets = (const float*)d_in[1];
    float* out = (float*)d_out;
    float* ws = (float*)d_ws;

    // workspace layout (floats)
    float* acc = ws;                               // 5*2*116 = 1160 floats
    size_t off = 1280;
    float* X1 = ws + off; off += (size_t)NIMG * 256 * 256;
    float* Y1 = ws + off; off += (size_t)NIMG * 256 * 256;
    float* X2 = ws + off; off += (size_t)NIMG * 128 * 128;
    float* Y2 = ws + off; off += (size_t)NIMG * 128 * 128;
    float* X3 = ws + off; off += (size_t)NIMG * 64 * 64;
    float* Y3 = ws + off; off += (size_t)NIMG * 64 * 64;
    float* X4 = ws + off; off += (size_t)NIMG * 32 * 32;
    float* Y4 = ws + off; off += (size_t)NIMG * 32 * 32;

    hipMemsetAsync(acc, 0, 1160 * sizeof(float), stream);

    const int Ms[5] = {502, 246, 118, 54, 22};

    // level 0: sigmoid + pool fused, binary targets -> SKIPYY, 5 blocks/CU
    {
        int N = 512;
        dim3 grid((N + TW - 1) / TW, N / TH, NIMG);
        ssim_kernel<true, true, true, false, 5><<<grid, 256, 0, stream>>>(
            logits, targets, N, Ms[0], acc, acc + NIMG, X1, Y1);
    }
    // level 1: N=256, wide tiles
    {
        int N = 256;
        dim3 grid((N + TW - 1) / TW, N / TH, NIMG);
        ssim_kernel<false, true, false, false, 4><<<grid, 256, 0, stream>>>(
            X1, Y1, N, Ms[1], acc + 2 * NIMG, acc + 3 * NIMG, X2, Y2);
    }
    // level 2: N=128, single x-tile
    {
        int N = 128;
        dim3 grid(1, N / TH, NIMG);
        ssim_kernel<false, true, false, true, 4><<<grid, 256, 0, stream>>>(
            X2, Y2, N, Ms[2], acc + 4 * NIMG, acc + 5 * NIMG, X3, Y3);
    }
    // level 3: N=64, single x-tile
    {
        int N = 64;
        dim3 grid(1, N / TH, NIMG);
        ssim_kernel<false, true, false, true, 4><<<grid, 256, 0, stream>>>(
            X3, Y3, N, Ms[3], acc + 6 * NIMG, acc + 7 * NIMG, X4, Y4);
    }
    // level 4: N=32, single x-tile, no pool
    {
        int N = 32;
        dim3 grid(1, N / TH, NIMG);
        ssim_kernel<false, false, false, true, 4><<<grid, 256, 0, stream>>>(
            X4, Y4, N, Ms[4], acc + 8 * NIMG, acc + 9 * NIMG, nullptr, nullptr);
    }

    finalize_kernel<<<1, 128, 0, stream>>>(acc, out);
}

// Round 5
// 493.468 us; speedup vs baseline: 1.0827x; 1.0827x over previous
//
#include <hip/hip_runtime.h>
#include <math.h>

#define NIMG 116          // 4*29 images
#define TW 118            // output tile width  (phase-1 columns = TW+10 = 128)
#define TH 16             // output tile height (strips of 8 rows, 2 strips)

// 11-tap Gaussian (size=11, sigma=1.5), fp32 values matching the reference.
static constexpr float W[11] = {
    0.00102838f, 0.00759876f, 0.03600078f, 0.10936075f, 0.21300554f,
    0.26601172f, 0.21300554f, 0.10936075f, 0.03600078f, 0.00759876f,
    0.00102838f};

__device__ __forceinline__ float frcp(float x) {
    return __builtin_amdgcn_rcpf(x);
}

__device__ __forceinline__ float fsig(float x) {
    float e = __builtin_amdgcn_exp2f(x * -1.4426950408889634f);
    return frcp(1.0f + e);
}

// One block per TWxTH output tile. Phase 1: vertical Gaussian of
// {X,Y,XX,(YY),XY} (thread-per-column, register accumulators, pool fused).
// Phase 2: horizontal Gaussian from LDS via swizzled float4 reads + SSIM map.
// SKIPYY: targets are binary (Y*Y==Y exactly) -> filter(YY)==filter(Y),
//         sigma2_sq = mu2 - mu2^2. Drops 1 of 5 quantities everywhere.
// NARROW: N <= 128 -> one x-tile covers all columns (phase-1 width 128).
// NOTE: LDS is padded to 40960 B regardless of Q. R4 measured that 32 KB ->
// 5 blocks/CU RAISES hbm traffic (FETCH 252->334 MB, WRITE 68->289 MB) and
// regresses 12%: locality beats occupancy here. Keep 4 blocks/CU.
template <bool SIG, bool POOL, bool SKIPYY, bool NARROW>
__global__ __launch_bounds__(256, 4)
void ssim_kernel(const float* __restrict__ X, const float* __restrict__ Y,
                 int N, int M,
                 float* __restrict__ accSsim, float* __restrict__ accCs,
                 float* __restrict__ poolX, float* __restrict__ poolY) {
    constexpr int Q = SKIPYY ? 4 : 5;          // mu1, mu2, xx, (yy), xy
    __shared__ float smem[5 * 16 * 128];       // padded: 40960 B -> 4 blocks/CU

    const int tid = threadIdx.x;
    const int img = blockIdx.z;
    const int ox0 = NARROW ? 0 : blockIdx.x * TW;
    const int oy0 = blockIdx.y * TH;
    const long base = (long)img * N * N;

    // ================= phase 1: vertical filter (+fused 2x2 pool) ==========
    const int c  = tid & 127;      // tile-local column 0..127
    const int s  = tid >> 7;       // strip 0/1 (rows 8s .. 8s+7 of v)
    const int ci = ox0 + c;        // global column
    const int cic = min(ci, N - 1);
    const int half = N >> 1;
    const int powned = NARROW ? N : min(TW, N - ox0);  // pool column ownership

    const float* __restrict__ Xb = X + base;
    const float* __restrict__ Yb = Y + base;

    float a0[8], a1[8], a2[8], a4[8];
    float a3[SKIPYY ? 1 : 8];
#pragma unroll
    for (int o = 0; o < 8; o++) {
        a0[o] = a1[o] = a2[o] = a4[o] = 0.f;
        if constexpr (!SKIPYY) a3[o] = 0.f;
    }

    float px = 0.f, py = 0.f;
#pragma unroll
    for (int i = 0; i < 18; i++) {
        int row = oy0 + 8 * s + i;
        int rc = min(row, N - 1);
        float x = Xb[(long)rc * N + cic];
        float y = Yb[(long)rc * N + cic];
        if (SIG) x = fsig(x);
        float xx = x * x, xy = x * y;
#pragma unroll
        for (int o = 0; o < 8; o++) {
            int t = i - o;
            if (t >= 0 && t < 11) {          // folds statically after unroll
                a0[o] = fmaf(W[t], x,  a0[o]);
                a1[o] = fmaf(W[t], y,  a1[o]);
                a2[o] = fmaf(W[t], xx, a2[o]);
                if constexpr (!SKIPYY) a3[o] = fmaf(W[t], y * y, a3[o]);
                a4[o] = fmaf(W[t], xy, a4[o]);
            }
        }
        if (POOL && (i & 1) && i < 8) {
            float cx = px + x, cy = py + y;
            float rx = __shfl_down(cx, 1, 64);   // column c+1 (same wave)
            float ry = __shfl_down(cy, 1, 64);
            if (!(c & 1) && c < powned) {
                int orow = (oy0 + 8 * s + i - 1) >> 1;
                int ocol = ci >> 1;
                long pb = (long)img * half * half + (long)orow * half + ocol;
                poolX[pb] = 0.25f * (cx + rx);
                poolY[pb] = 0.25f * (cy + ry);
            }
        }
        px = x; py = y;
    }

    // store v to LDS, column-swizzled by 4*row to spread b128 read banks
#pragma unroll
    for (int o = 0; o < 8; o++) {
        int r = 8 * s + o;
        int cc = (c + 4 * r) & 127;
        smem[0 * 2048 + r * 128 + cc] = a0[o];
        smem[1 * 2048 + r * 128 + cc] = a1[o];
        smem[2 * 2048 + r * 128 + cc] = a2[o];
        if constexpr (!SKIPYY) smem[3 * 2048 + r * 128 + cc] = a3[o];
        smem[(Q - 1) * 2048 + r * 128 + cc] = a4[o];
    }
    __syncthreads();

    // ================= phase 2: horizontal filter + SSIM ====================
    const float C1 = 1e-4f, C2 = 9e-4f;
    float scs = 0.f, sss = 0.f;
    {
        const int r = tid >> 4;    // output row within tile
        const int k = tid & 15;    // 8-px column segment
        if (k < 15) {              // segment base 8k must be < 118
            float acc[Q][8];
#pragma unroll
            for (int q = 0; q < Q; q++) {
                float rg[20];
#pragma unroll
                for (int j5 = 0; j5 < 5; j5++) {
                    int col = (8 * k + 4 * j5 + 4 * r) & 127;   // swizzled chunk
                    const float4 v4 = *(const float4*)&smem[q * 2048 + r * 128 + col];
                    rg[4 * j5 + 0] = v4.x; rg[4 * j5 + 1] = v4.y;
                    rg[4 * j5 + 2] = v4.z; rg[4 * j5 + 3] = v4.w;
                }
#pragma unroll
                for (int j = 0; j < 8; j++) {
                    float a = 0.f;
#pragma unroll
                    for (int t = 0; t < 11; t++) a = fmaf(W[t], rg[j + t], a);
                    acc[q][j] = a;
                }
            }
            int gy = oy0 + r;
#pragma unroll
            for (int j = 0; j < 8; j++) {
                int lc = 8 * k + j;
                int gx = ox0 + lc;
                if (lc < TW && gx < M && gy < M) {
                    float mu1 = acc[0][j], mu2 = acc[1][j];
                    float exx = acc[2][j], exy = acc[Q - 1][j];
                    float m11 = mu1 * mu1, m22 = mu2 * mu2, m12 = mu1 * mu2;
                    float s1 = exx - m11;
                    float s2 = SKIPYY ? (mu2 - m22) : (acc[3][j] - m22);
                    float s12 = exy - m12;
                    float cs = (2.f * s12 + C2) * frcp(s1 + s2 + C2);
                    float ssim = (2.f * m12 + C1) * frcp(m11 + m22 + C1) * cs;
                    scs += cs; sss += ssim;
                }
            }
        }
    }

    // block reduction (reuse smem after barrier)
    for (int off = 32; off > 0; off >>= 1) {
        scs += __shfl_down(scs, off, 64);
        sss += __shfl_down(sss, off, 64);
    }
    __syncthreads();
    int lane = tid & 63, wv = tid >> 6;
    if (lane == 0) { smem[wv] = scs; smem[4 + wv] = sss; }
    __syncthreads();
    if (tid == 0) {
        atomicAdd(&accCs[img],   smem[0] + smem[1] + smem[2] + smem[3]);
        atomicAdd(&accSsim[img], smem[4] + smem[5] + smem[6] + smem[7]);
    }
}

// acc layout: level l -> [l*2*NIMG .. +NIMG) ssim sums, [+NIMG .. +2*NIMG) cs sums
__global__ __launch_bounds__(128)
void finalize_kernel(const float* __restrict__ acc, float* __restrict__ out) {
    const float wts[5] = {0.0448f, 0.2856f, 0.3001f, 0.2363f, 0.1333f};
    const int Ms[5] = {502, 246, 118, 54, 22};
    int t = threadIdx.x;
    float v = 0.f;
    if (t < NIMG) {
        float prod = 1.f;
#pragma unroll
        for (int l = 0; l < 5; l++) {
            float inv = 1.0f / ((float)Ms[l] * (float)Ms[l]);
            float m = (l < 4) ? acc[l * 2 * NIMG + NIMG + t] * inv   // cs mean
                              : acc[l * 2 * NIMG + t] * inv;          // ssim mean
            m = fmaxf(m, 0.f);                                        // relu
            prod *= powf(m, wts[l]);
        }
        v = prod;
    }
    for (int off = 32; off > 0; off >>= 1) v += __shfl_down(v, off, 64);
    __shared__ float red[2];
    if ((t & 63) == 0) red[t >> 6] = v;
    __syncthreads();
    if (t == 0) out[0] = 1.0f - (red[0] + red[1]) / (float)NIMG;
}

extern "C" void kernel_launch(void* const* d_in, const int* in_sizes, int n_in,
                              void* d_out, int out_size, void* d_ws, size_t ws_size,
                              hipStream_t stream) {
    const float* logits = (const float*)d_in[0];
    const float* targets = (const float*)d_in[1];
    float* out = (float*)d_out;
    float* ws = (float*)d_ws;

    // workspace layout (floats)
    float* acc = ws;                               // 5*2*116 = 1160 floats
    size_t off = 1280;
    float* X1 = ws + off; off += (size_t)NIMG * 256 * 256;
    float* Y1 = ws + off; off += (size_t)NIMG * 256 * 256;
    float* X2 = ws + off; off += (size_t)NIMG * 128 * 128;
    float* Y2 = ws + off; off += (size_t)NIMG * 128 * 128;
    float* X3 = ws + off; off += (size_t)NIMG * 64 * 64;
    float* Y3 = ws + off; off += (size_t)NIMG * 64 * 64;
    float* X4 = ws + off; off += (size_t)NIMG * 32 * 32;
    float* Y4 = ws + off; off += (size_t)NIMG * 32 * 32;

    hipMemsetAsync(acc, 0, 1160 * sizeof(float), stream);

    const int Ms[5] = {502, 246, 118, 54, 22};

    // level 0: sigmoid + pool fused, binary targets -> SKIPYY
    {
        int N = 512;
        dim3 grid((N + TW - 1) / TW, N / TH, NIMG);
        ssim_kernel<true, true, true, false><<<grid, 256, 0, stream>>>(
            logits, targets, N, Ms[0], acc, acc + NIMG, X1, Y1);
    }
    // level 1: N=256, wide tiles
    {
        int N = 256;
        dim3 grid((N + TW - 1) / TW, N / TH, NIMG);
        ssim_kernel<false, true, false, false><<<grid, 256, 0, stream>>>(
            X1, Y1, N, Ms[1], acc + 2 * NIMG, acc + 3 * NIMG, X2, Y2);
    }
    // level 2: N=128, single x-tile
    {
        int N = 128;
        dim3 grid(1, N / TH, NIMG);
        ssim_kernel<false, true, false, true><<<grid, 256, 0, stream>>>(
            X2, Y2, N, Ms[2], acc + 4 * NIMG, acc + 5 * NIMG, X3, Y3);
    }
    // level 3: N=64, single x-tile
    {
        int N = 64;
        dim3 grid(1, N / TH, NIMG);
        ssim_kernel<false, true, false, true><<<grid, 256, 0, stream>>>(
            X3, Y3, N, Ms[3], acc + 6 * NIMG, acc + 7 * NIMG, X4, Y4);
    }
    // level 4: N=32, single x-tile, no pool
    {
        int N = 32;
        dim3 grid(1, N / TH, NIMG);
        ssim_kernel<false, false, false, true><<<grid, 256, 0, stream>>>(
            X4, Y4, N, Ms[4], acc + 8 * NIMG, acc + 9 * NIMG, nullptr, nullptr);
    }

    finalize_kernel<<<1, 128, 0, stream>>>(acc, out);
}

// Round 6
// 432.541 us; speedup vs baseline: 1.2352x; 1.1409x over previous
//
#include <hip/hip_runtime.h>
#include <math.h>

#define NIMG 116          // 4*29 images
#define TW 118            // output tile width  (phase-1 columns = TW+10 = 128)
#define TH 16             // output tile height (strips of 8 rows, 2 strips)

// 11-tap Gaussian (size=11, sigma=1.5), fp32 values matching the reference.
static constexpr float W[11] = {
    0.00102838f, 0.00759876f, 0.03600078f, 0.10936075f, 0.21300554f,
    0.26601172f, 0.21300554f, 0.10936075f, 0.03600078f, 0.00759876f,
    0.00102838f};

__device__ __forceinline__ float frcp(float x) {
    return __builtin_amdgcn_rcpf(x);
}

__device__ __forceinline__ float fsig(float x) {
    float e = __builtin_amdgcn_exp2f(x * -1.4426950408889634f);
    return frcp(1.0f + e);
}

// One block per TWxTH output tile. Phase 1: batch-load 18 rows/thread into
// registers (latency hiding), then vertical Gaussian of {X,Y,XX,(YY),XY}
// with fused 2x2 pool. Phase 2: horizontal Gaussian from LDS via swizzled
// float4 reads + SSIM map.
// SKIPYY: targets are binary (Y*Y==Y exactly) -> filter(YY)==filter(Y),
//         sigma2_sq = mu2 - mu2^2.
// NARROW: N <= 128 -> one x-tile covers all columns.
// NOTE: LDS padded to 40960 B regardless of Q. R4 measured that 32 KB ->
// 5 blocks/CU RAISES hbm traffic (FETCH 252->334 MB, WRITE 68->289 MB) and
// regresses 12%: locality beats occupancy here. Keep 4 blocks/CU.
template <bool SIG, bool POOL, bool SKIPYY, bool NARROW>
__global__ __launch_bounds__(256, 4)
void ssim_kernel(const float* __restrict__ X, const float* __restrict__ Y,
                 int N, int M,
                 float* __restrict__ accSsim, float* __restrict__ accCs,
                 float* __restrict__ poolX, float* __restrict__ poolY) {
    constexpr int Q = SKIPYY ? 4 : 5;          // mu1, mu2, xx, (yy), xy
    __shared__ float smem[5 * 16 * 128];       // padded: 40960 B -> 4 blocks/CU

    const int tid = threadIdx.x;
    const int img = blockIdx.z;
    const int ox0 = NARROW ? 0 : blockIdx.x * TW;
    const int oy0 = blockIdx.y * TH;
    const long base = (long)img * N * N;

    // ================= phase 1: batch load ==================================
    const int c  = tid & 127;      // tile-local column 0..127
    const int s  = tid >> 7;       // strip 0/1 (rows 8s .. 8s+7 of v)
    const int ci = ox0 + c;        // global column
    const int half = N >> 1;
    const int powned = NARROW ? N : min(TW, N - ox0);  // pool column ownership

    const float* __restrict__ Xb = X + base;
    const float* __restrict__ Yb = Y + base;

    // interior: no row/col clamping anywhere in this block (block-uniform)
    const bool interior = (oy0 + 25 < N) && (ox0 + 127 < N);

    float xv[18], yv[18];
    if (interior) {
        const float* __restrict__ xp = Xb + (long)(oy0 + 8 * s) * N + ci;
        const float* __restrict__ yp = Yb + (long)(oy0 + 8 * s) * N + ci;
#pragma unroll
        for (int i = 0; i < 18; i++) {
            xv[i] = xp[(long)i * N];
            yv[i] = yp[(long)i * N];
        }
    } else {
        const int cic = min(ci, N - 1);
#pragma unroll
        for (int i = 0; i < 18; i++) {
            int rc = min(oy0 + 8 * s + i, N - 1);
            xv[i] = Xb[(long)rc * N + cic];
            yv[i] = Yb[(long)rc * N + cic];
        }
    }
    if (SIG) {
#pragma unroll
        for (int i = 0; i < 18; i++) xv[i] = fsig(xv[i]);
    }

    // ================= phase 1b: vertical filter (+fused 2x2 pool) ==========
    float a0[8], a1[8], a2[8], a4[8];
    float a3[SKIPYY ? 1 : 8];
#pragma unroll
    for (int o = 0; o < 8; o++) {
        a0[o] = a1[o] = a2[o] = a4[o] = 0.f;
        if constexpr (!SKIPYY) a3[o] = 0.f;
    }

#pragma unroll
    for (int i = 0; i < 18; i++) {
        float x = xv[i], y = yv[i];
        float xx = x * x, xy = x * y;
#pragma unroll
        for (int o = 0; o < 8; o++) {
            int t = i - o;
            if (t >= 0 && t < 11) {          // folds statically after unroll
                a0[o] = fmaf(W[t], x,  a0[o]);
                a1[o] = fmaf(W[t], y,  a1[o]);
                a2[o] = fmaf(W[t], xx, a2[o]);
                if constexpr (!SKIPYY) a3[o] = fmaf(W[t], y * y, a3[o]);
                a4[o] = fmaf(W[t], xy, a4[o]);
            }
        }
        if (POOL && (i & 1) && i < 8) {
            float cx = xv[i - 1] + x, cy = yv[i - 1] + y;
            float rx = __shfl_down(cx, 1, 64);   // column c+1 (same wave)
            float ry = __shfl_down(cy, 1, 64);
            if (!(c & 1) && c < powned) {
                int orow = (oy0 + 8 * s + i - 1) >> 1;
                int ocol = ci >> 1;
                long pb = (long)img * half * half + (long)orow * half + ocol;
                poolX[pb] = 0.25f * (cx + rx);
                poolY[pb] = 0.25f * (cy + ry);
            }
        }
    }

    // store v to LDS, column-swizzled by 4*row to spread b128 read banks
#pragma unroll
    for (int o = 0; o < 8; o++) {
        int r = 8 * s + o;
        int cc = (c + 4 * r) & 127;
        smem[0 * 2048 + r * 128 + cc] = a0[o];
        smem[1 * 2048 + r * 128 + cc] = a1[o];
        smem[2 * 2048 + r * 128 + cc] = a2[o];
        if constexpr (!SKIPYY) smem[3 * 2048 + r * 128 + cc] = a3[o];
        smem[(Q - 1) * 2048 + r * 128 + cc] = a4[o];
    }
    __syncthreads();

    // ================= phase 2: horizontal filter + SSIM ====================
    const float C1 = 1e-4f, C2 = 9e-4f;
    float scs = 0.f, sss = 0.f;
    {
        const int r = tid >> 4;    // output row within tile
        const int k = tid & 15;    // 8-px column segment
        if (k < 15) {              // segment base 8k must be < 118
            float acc[Q][8];
#pragma unroll
            for (int q = 0; q < Q; q++) {
                float rg[20];
#pragma unroll
                for (int j5 = 0; j5 < 5; j5++) {
                    int col = (8 * k + 4 * j5 + 4 * r) & 127;   // swizzled chunk
                    const float4 v4 = *(const float4*)&smem[q * 2048 + r * 128 + col];
                    rg[4 * j5 + 0] = v4.x; rg[4 * j5 + 1] = v4.y;
                    rg[4 * j5 + 2] = v4.z; rg[4 * j5 + 3] = v4.w;
                }
#pragma unroll
                for (int j = 0; j < 8; j++) {
                    float a = 0.f;
#pragma unroll
                    for (int t = 0; t < 11; t++) a = fmaf(W[t], rg[j + t], a);
                    acc[q][j] = a;
                }
            }
            int gy = oy0 + r;
#pragma unroll
            for (int j = 0; j < 8; j++) {
                int lc = 8 * k + j;
                int gx = ox0 + lc;
                if (lc < TW && gx < M && gy < M) {
                    float mu1 = acc[0][j], mu2 = acc[1][j];
                    float exx = acc[2][j], exy = acc[Q - 1][j];
                    float m11 = mu1 * mu1, m22 = mu2 * mu2, m12 = mu1 * mu2;
                    float s1 = exx - m11;
                    float s2 = SKIPYY ? (mu2 - m22) : (acc[3][j] - m22);
                    float s12 = exy - m12;
                    float cs = (2.f * s12 + C2) * frcp(s1 + s2 + C2);
                    float ssim = (2.f * m12 + C1) * frcp(m11 + m22 + C1) * cs;
                    scs += cs; sss += ssim;
                }
            }
        }
    }

    // block reduction (reuse smem after barrier)
    for (int off = 32; off > 0; off >>= 1) {
        scs += __shfl_down(scs, off, 64);
        sss += __shfl_down(sss, off, 64);
    }
    __syncthreads();
    int lane = tid & 63, wv = tid >> 6;
    if (lane == 0) { smem[wv] = scs; smem[4 + wv] = sss; }
    __syncthreads();
    if (tid == 0) {
        atomicAdd(&accCs[img],   smem[0] + smem[1] + smem[2] + smem[3]);
        atomicAdd(&accSsim[img], smem[4] + smem[5] + smem[6] + smem[7]);
    }
}

// acc layout: level l -> [l*2*NIMG .. +NIMG) ssim sums, [+NIMG .. +2*NIMG) cs sums
__global__ __launch_bounds__(128)
void finalize_kernel(const float* __restrict__ acc, float* __restrict__ out) {
    const float wts[5] = {0.0448f, 0.2856f, 0.3001f, 0.2363f, 0.1333f};
    const int Ms[5] = {502, 246, 118, 54, 22};
    int t = threadIdx.x;
    float v = 0.f;
    if (t < NIMG) {
        float prod = 1.f;
#pragma unroll
        for (int l = 0; l < 5; l++) {
            float inv = 1.0f / ((float)Ms[l] * (float)Ms[l]);
            float m = (l < 4) ? acc[l * 2 * NIMG + NIMG + t] * inv   // cs mean
                              : acc[l * 2 * NIMG + t] * inv;          // ssim mean
            m = fmaxf(m, 0.f);                                        // relu
            prod *= powf(m, wts[l]);
        }
        v = prod;
    }
    for (int off = 32; off > 0; off >>= 1) v += __shfl_down(v, off, 64);
    __shared__ float red[2];
    if ((t & 63) == 0) red[t >> 6] = v;
    __syncthreads();
    if (t == 0) out[0] = 1.0f - (red[0] + red[1]) / (float)NIMG;
}

extern "C" void kernel_launch(void* const* d_in, const int* in_sizes, int n_in,
                              void* d_out, int out_size, void* d_ws, size_t ws_size,
                              hipStream_t stream) {
    const float* logits = (const float*)d_in[0];
    const float* targets = (const float*)d_in[1];
    float* out = (float*)d_out;
    float* ws = (float*)d_ws;

    // workspace layout (floats)
    float* acc = ws;                               // 5*2*116 = 1160 floats
    size_t off = 1280;
    float* X1 = ws + off; off += (size_t)NIMG * 256 * 256;
    float* Y1 = ws + off; off += (size_t)NIMG * 256 * 256;
    float* X2 = ws + off; off += (size_t)NIMG * 128 * 128;
    float* Y2 = ws + off; off += (size_t)NIMG * 128 * 128;
    float* X3 = ws + off; off += (size_t)NIMG * 64 * 64;
    float* Y3 = ws + off; off += (size_t)NIMG * 64 * 64;
    float* X4 = ws + off; off += (size_t)NIMG * 32 * 32;
    float* Y4 = ws + off; off += (size_t)NIMG * 32 * 32;

    hipMemsetAsync(acc, 0, 1160 * sizeof(float), stream);

    const int Ms[5] = {502, 246, 118, 54, 22};

    // level 0: sigmoid + pool fused, binary targets -> SKIPYY
    {
        int N = 512;
        dim3 grid((N + TW - 1) / TW, N / TH, NIMG);
        ssim_kernel<true, true, true, false><<<grid, 256, 0, stream>>>(
            logits, targets, N, Ms[0], acc, acc + NIMG, X1, Y1);
    }
    // level 1: N=256, wide tiles
    {
        int N = 256;
        dim3 grid((N + TW - 1) / TW, N / TH, NIMG);
        ssim_kernel<false, true, false, false><<<grid, 256, 0, stream>>>(
            X1, Y1, N, Ms[1], acc + 2 * NIMG, acc + 3 * NIMG, X2, Y2);
    }
    // level 2: N=128, single x-tile
    {
        int N = 128;
        dim3 grid(1, N / TH, NIMG);
        ssim_kernel<false, true, false, true><<<grid, 256, 0, stream>>>(
            X2, Y2, N, Ms[2], acc + 4 * NIMG, acc + 5 * NIMG, X3, Y3);
    }
    // level 3: N=64, single x-tile
    {
        int N = 64;
        dim3 grid(1, N / TH, NIMG);
        ssim_kernel<false, true, false, true><<<grid, 256, 0, stream>>>(
            X3, Y3, N, Ms[3], acc + 6 * NIMG, acc + 7 * NIMG, X4, Y4);
    }
    // level 4: N=32, single x-tile, no pool
    {
        int N = 32;
        dim3 grid(1, N / TH, NIMG);
        ssim_kernel<false, false, false, true><<<grid, 256, 0, stream>>>(
            X4, Y4, N, Ms[4], acc + 8 * NIMG, acc + 9 * NIMG, nullptr, nullptr);
    }

    finalize_kernel<<<1, 128, 0, stream>>>(acc, out);
}

// Round 7
// 421.384 us; speedup vs baseline: 1.2679x; 1.0265x over previous
//
#include <hip/hip_runtime.h>
#include <math.h>

#define NIMG 116          // 4*29 images
#define TW 118            // output tile width  (phase-1 columns = TW+10 = 128)
#define TH 16             // output tile height (strips of 8 rows, 2 strips)

// 11-tap Gaussian (size=11, sigma=1.5), fp32 values matching the reference.
static constexpr float W[11] = {
    0.00102838f, 0.00759876f, 0.03600078f, 0.10936075f, 0.21300554f,
    0.26601172f, 0.21300554f, 0.10936075f, 0.03600078f, 0.00759876f,
    0.00102838f};

__device__ __forceinline__ float frcp(float x) {
    return __builtin_amdgcn_rcpf(x);
}

__device__ __forceinline__ float fsig(float x) {
    float e = __builtin_amdgcn_exp2f(x * -1.4426950408889634f);
    return frcp(1.0f + e);
}

// One block per TWxTH output tile. Phase 1: batch-load 18 rows/thread into
// registers with a sched_barrier fence (keeps all loads in flight; R6's
// version let the compiler re-fold loads into the FMA loop, VGPR=56), then
// vertical Gaussian of {X,Y,XX,(YY),XY}; 2x2 pool computed AFTER the FMA
// loop from live registers (no mid-loop DS stalls). Phase 2: horizontal
// Gaussian from LDS via swizzled float4 reads + SSIM map.
// SKIPYY: targets are binary (Y*Y==Y exactly) -> filter(YY)==filter(Y),
//         sigma2_sq = mu2 - mu2^2.
// NARROW: N <= 128 -> one x-tile covers all columns.
// NOTE: LDS padded to 40960 B regardless of Q. R4 measured that 32 KB ->
// 5 blocks/CU RAISES hbm traffic (FETCH 252->334 MB, WRITE 68->289 MB) and
// regresses 12%: locality beats occupancy here. Keep 4 blocks/CU.
template <bool SIG, bool POOL, bool SKIPYY, bool NARROW>
__global__ __launch_bounds__(256, 4)
void ssim_kernel(const float* __restrict__ X, const float* __restrict__ Y,
                 int N, int M,
                 float* __restrict__ accSsim, float* __restrict__ accCs,
                 float* __restrict__ poolX, float* __restrict__ poolY) {
    constexpr int Q = SKIPYY ? 4 : 5;          // mu1, mu2, xx, (yy), xy
    __shared__ float smem[5 * 16 * 128];       // padded: 40960 B -> 4 blocks/CU

    const int tid = threadIdx.x;
    const int img = blockIdx.z;
    const int ox0 = NARROW ? 0 : blockIdx.x * TW;
    const int oy0 = blockIdx.y * TH;
    const long base = (long)img * N * N;

    // ================= phase 1: batch load ==================================
    const int c  = tid & 127;      // tile-local column 0..127
    const int s  = tid >> 7;       // strip 0/1 (rows 8s .. 8s+7 of v)
    const int ci = ox0 + c;        // global column
    const int half = N >> 1;
    const int powned = NARROW ? N : min(TW, N - ox0);  // pool column ownership

    const float* __restrict__ Xb = X + base;
    const float* __restrict__ Yb = Y + base;

    // interior: no row/col clamping anywhere in this block (block-uniform)
    const bool interior = (oy0 + 25 < N) && (ox0 + 127 < N);

    float xv[18], yv[18];
    if (interior) {
        const float* __restrict__ xp = Xb + (long)(oy0 + 8 * s) * N + ci;
        const float* __restrict__ yp = Yb + (long)(oy0 + 8 * s) * N + ci;
#pragma unroll
        for (int i = 0; i < 18; i++) {
            xv[i] = xp[(long)i * N];
            yv[i] = yp[(long)i * N];
        }
    } else {
        const int cic = min(ci, N - 1);
#pragma unroll
        for (int i = 0; i < 18; i++) {
            int rc = min(oy0 + 8 * s + i, N - 1);
            xv[i] = Xb[(long)rc * N + cic];
            yv[i] = Yb[(long)rc * N + cic];
        }
    }
    // Fence: keep ALL 36 loads issued before any compute is scheduled.
    // Without this the scheduler sinks loads into the FMA loop to minimize
    // VGPRs (R6 measured VGPR=56 -> only ~8 loads in flight).
    __builtin_amdgcn_sched_barrier(0);

    if (SIG) {
#pragma unroll
        for (int i = 0; i < 18; i++) xv[i] = fsig(xv[i]);
    }

    // ================= phase 1b: vertical filter ============================
    float a0[8], a1[8], a2[8], a4[8];
    float a3[SKIPYY ? 1 : 8];
#pragma unroll
    for (int o = 0; o < 8; o++) {
        a0[o] = a1[o] = a2[o] = a4[o] = 0.f;
        if constexpr (!SKIPYY) a3[o] = 0.f;
    }

#pragma unroll
    for (int i = 0; i < 18; i++) {
        float x = xv[i], y = yv[i];
        float xx = x * x, xy = x * y;
#pragma unroll
        for (int o = 0; o < 8; o++) {
            int t = i - o;
            if (t >= 0 && t < 11) {          // folds statically after unroll
                a0[o] = fmaf(W[t], x,  a0[o]);
                a1[o] = fmaf(W[t], y,  a1[o]);
                a2[o] = fmaf(W[t], xx, a2[o]);
                if constexpr (!SKIPYY) a3[o] = fmaf(W[t], y * y, a3[o]);
                a4[o] = fmaf(W[t], xy, a4[o]);
            }
        }
    }

    // ================= phase 1c: fused 2x2 pool (batched shuffles) ==========
    if (POOL) {
        float cx[4], cy[4];
#pragma unroll
        for (int p = 0; p < 4; p++) {
            cx[p] = xv[2 * p] + xv[2 * p + 1];
            cy[p] = yv[2 * p] + yv[2 * p + 1];
        }
#pragma unroll
        for (int p = 0; p < 4; p++) {
            float rx = __shfl_down(cx[p], 1, 64);   // column c+1 (same wave)
            float ry = __shfl_down(cy[p], 1, 64);
            if (!(c & 1) && c < powned) {
                int orow = (oy0 + 8 * s + 2 * p) >> 1;
                int ocol = ci >> 1;
                long pb = (long)img * half * half + (long)orow * half + ocol;
                poolX[pb] = 0.25f * (cx[p] + rx);
                poolY[pb] = 0.25f * (cy[p] + ry);
            }
        }
    }

    // store v to LDS, column-swizzled by 4*row to spread b128 read banks
#pragma unroll
    for (int o = 0; o < 8; o++) {
        int r = 8 * s + o;
        int cc = (c + 4 * r) & 127;
        smem[0 * 2048 + r * 128 + cc] = a0[o];
        smem[1 * 2048 + r * 128 + cc] = a1[o];
        smem[2 * 2048 + r * 128 + cc] = a2[o];
        if constexpr (!SKIPYY) smem[3 * 2048 + r * 128 + cc] = a3[o];
        smem[(Q - 1) * 2048 + r * 128 + cc] = a4[o];
    }
    __syncthreads();

    // ================= phase 2: horizontal filter + SSIM ====================
    const float C1 = 1e-4f, C2 = 9e-4f;
    float scs = 0.f, sss = 0.f;
    {
        const int r = tid >> 4;    // output row within tile
        const int k = tid & 15;    // 8-px column segment
        if (k < 15) {              // segment base 8k must be < 118
            float acc[Q][8];
#pragma unroll
            for (int q = 0; q < Q; q++) {
                float rg[20];
#pragma unroll
                for (int j5 = 0; j5 < 5; j5++) {
                    int col = (8 * k + 4 * j5 + 4 * r) & 127;   // swizzled chunk
                    const float4 v4 = *(const float4*)&smem[q * 2048 + r * 128 + col];
                    rg[4 * j5 + 0] = v4.x; rg[4 * j5 + 1] = v4.y;
                    rg[4 * j5 + 2] = v4.z; rg[4 * j5 + 3] = v4.w;
                }
#pragma unroll
                for (int j = 0; j < 8; j++) {
                    float a = 0.f;
#pragma unroll
                    for (int t = 0; t < 11; t++) a = fmaf(W[t], rg[j + t], a);
                    acc[q][j] = a;
                }
            }
            int gy = oy0 + r;
#pragma unroll
            for (int j = 0; j < 8; j++) {
                int lc = 8 * k + j;
                int gx = ox0 + lc;
                if (lc < TW && gx < M && gy < M) {
                    float mu1 = acc[0][j], mu2 = acc[1][j];
                    float exx = acc[2][j], exy = acc[Q - 1][j];
                    float m11 = mu1 * mu1, m22 = mu2 * mu2, m12 = mu1 * mu2;
                    float s1 = exx - m11;
                    float s2 = SKIPYY ? (mu2 - m22) : (acc[3][j] - m22);
                    float s12 = exy - m12;
                    float cs = (2.f * s12 + C2) * frcp(s1 + s2 + C2);
                    float ssim = (2.f * m12 + C1) * frcp(m11 + m22 + C1) * cs;
                    scs += cs; sss += ssim;
                }
            }
        }
    }

    // block reduction (reuse smem after barrier)
    for (int off = 32; off > 0; off >>= 1) {
        scs += __shfl_down(scs, off, 64);
        sss += __shfl_down(sss, off, 64);
    }
    __syncthreads();
    int lane = tid & 63, wv = tid >> 6;
    if (lane == 0) { smem[wv] = scs; smem[4 + wv] = sss; }
    __syncthreads();
    if (tid == 0) {
        atomicAdd(&accCs[img],   smem[0] + smem[1] + smem[2] + smem[3]);
        atomicAdd(&accSsim[img], smem[4] + smem[5] + smem[6] + smem[7]);
    }
}

// acc layout: level l -> [l*2*NIMG .. +NIMG) ssim sums, [+NIMG .. +2*NIMG) cs sums
__global__ __launch_bounds__(128)
void finalize_kernel(const float* __restrict__ acc, float* __restrict__ out) {
    const float wts[5] = {0.0448f, 0.2856f, 0.3001f, 0.2363f, 0.1333f};
    const int Ms[5] = {502, 246, 118, 54, 22};
    int t = threadIdx.x;
    float v = 0.f;
    if (t < NIMG) {
        float prod = 1.f;
#pragma unroll
        for (int l = 0; l < 5; l++) {
            float inv = 1.0f / ((float)Ms[l] * (float)Ms[l]);
            float m = (l < 4) ? acc[l * 2 * NIMG + NIMG + t] * inv   // cs mean
                              : acc[l * 2 * NIMG + t] * inv;          // ssim mean
            m = fmaxf(m, 0.f);                                        // relu
            prod *= powf(m, wts[l]);
        }
        v = prod;
    }
    for (int off = 32; off > 0; off >>= 1) v += __shfl_down(v, off, 64);
    __shared__ float red[2];
    if ((t & 63) == 0) red[t >> 6] = v;
    __syncthreads();
    if (t == 0) out[0] = 1.0f - (red[0] + red[1]) / (float)NIMG;
}

extern "C" void kernel_launch(void* const* d_in, const int* in_sizes, int n_in,
                              void* d_out, int out_size, void* d_ws, size_t ws_size,
                              hipStream_t stream) {
    const float* logits = (const float*)d_in[0];
    const float* targets = (const float*)d_in[1];
    float* out = (float*)d_out;
    float* ws = (float*)d_ws;

    // workspace layout (floats)
    float* acc = ws;                               // 5*2*116 = 1160 floats
    size_t off = 1280;
    float* X1 = ws + off; off += (size_t)NIMG * 256 * 256;
    float* Y1 = ws + off; off += (size_t)NIMG * 256 * 256;
    float* X2 = ws + off; off += (size_t)NIMG * 128 * 128;
    float* Y2 = ws + off; off += (size_t)NIMG * 128 * 128;
    float* X3 = ws + off; off += (size_t)NIMG * 64 * 64;
    float* Y3 = ws + off; off += (size_t)NIMG * 64 * 64;
    float* X4 = ws + off; off += (size_t)NIMG * 32 * 32;
    float* Y4 = ws + off; off += (size_t)NIMG * 32 * 32;

    hipMemsetAsync(acc, 0, 1160 * sizeof(float), stream);

    const int Ms[5] = {502, 246, 118, 54, 22};

    // level 0: sigmoid + pool fused, binary targets -> SKIPYY
    {
        int N = 512;
        dim3 grid((N + TW - 1) / TW, N / TH, NIMG);
        ssim_kernel<true, true, true, false><<<grid, 256, 0, stream>>>(
            logits, targets, N, Ms[0], acc, acc + NIMG, X1, Y1);
    }
    // level 1: N=256, wide tiles
    {
        int N = 256;
        dim3 grid((N + TW - 1) / TW, N / TH, NIMG);
        ssim_kernel<false, true, false, false><<<grid, 256, 0, stream>>>(
            X1, Y1, N, Ms[1], acc + 2 * NIMG, acc + 3 * NIMG, X2, Y2);
    }
    // level 2: N=128, single x-tile
    {
        int N = 128;
        dim3 grid(1, N / TH, NIMG);
        ssim_kernel<false, true, false, true><<<grid, 256, 0, stream>>>(
            X2, Y2, N, Ms[2], acc + 4 * NIMG, acc + 5 * NIMG, X3, Y3);
    }
    // level 3: N=64, single x-tile
    {
        int N = 64;
        dim3 grid(1, N / TH, NIMG);
        ssim_kernel<false, true, false, true><<<grid, 256, 0, stream>>>(
            X3, Y3, N, Ms[3], acc + 6 * NIMG, acc + 7 * NIMG, X4, Y4);
    }
    // level 4: N=32, single x-tile, no pool
    {
        int N = 32;
        dim3 grid(1, N / TH, NIMG);
        ssim_kernel<false, false, false, true><<<grid, 256, 0, stream>>>(
            X4, Y4, N, Ms[4], acc + 8 * NIMG, acc + 9 * NIMG, nullptr, nullptr);
    }

    finalize_kernel<<<1, 128, 0, stream>>>(acc, out);
}